// Round 20
// baseline (113.992 us; speedup 1.0000x reference)
//
#include <hip/hip_runtime.h>

// B,C,H,W = 4,64,64,64 ; N = 4096 ; d = 8
#define BB 4
#define CC 64
#define NN 4096

typedef __attribute__((ext_vector_type(8))) short short8;
typedef __attribute__((ext_vector_type(4))) float f32x4;
typedef __attribute__((ext_vector_type(4))) unsigned uint4v;

__device__ inline ushort f2bf(float x) {                 // RNE float->bf16
    unsigned u = __float_as_uint(x);
    return (ushort)((u + 0x7fff + ((u >> 16) & 1)) >> 16);
}
__device__ inline float bf2f(ushort h) { return __uint_as_float(((unsigned)h) << 16); }

__device__ inline unsigned cvt_pk_bf16(float a, float b) {   // lo=bf16(a), hi=bf16(b)
    unsigned r;
    asm("v_cvt_pk_bf16_f32 %0, %1, %2" : "=v"(r) : "v"(a), "v"(b));
    return r;
}

// ws layout (ushort):
//   qTp [B][N][32] : q0..q7, q0h,q1h,q0l,q1l, 0*20                     (1 MB)
//   kTp [B][N][32] : k0..k7, col,row,col,row, 0*20                     (1 MB)
//   vsw [B][64 tiles][2 sb][4 g][64 lanes][8 jj]                       (2 MB)
//     KEY-PERMUTED B-frag: physical key j (kg=j>>4, qd=(j>>2)&3, r=j&3) is
//     stored at (sb=kg>>1, lane=qd*16+(e&15), jj=((kg&1)<<2)|r) so the PV
//     A-operand is exactly the lane-local cvt_pk output of the S-MFMA.
//
// R20: two zero-correctness-risk edits on the verified R15/R19 base
// (109.5us, absmax 0.046875):
//   (a) qkv: full unroll of the 64-iter c-loops (was unroll 8) -> more
//       independent loads in flight on the latency chains. Same FMA order.
//   (b) attn: T5 s_setprio(1)/(0) around the shared-PV MFMA cluster.
//       Waves are barrier-free in the main loop (independent phases) ->
//       the regime where T5 measured +4-7% (m191), not the lockstep null.
//
// MEASURED BUDGET: fill ~41us + fixed overhead ~32us (harness, immovable) +
// qkv 11.8us + attn ~24us = ~109.5us.
//
// EMPIRICAL RULE (R2/R3/R4/R7 vs R1/R8-R19): never stage K/V tiles into
// short8 REGISTER ARRAYS in attn; all kf/vf loads inline single-vars.

// ---------------------------------------------------------------------------
// Kernel 1: QKV projection — R11 structure; c-loops fully unrolled (bit-
// identical arithmetic, per-thread FMA order unchanged).
// ---------------------------------------------------------------------------
__global__ __launch_bounds__(512) void qkv_kernel(
    const float* __restrict__ x,
    const float* __restrict__ Wq, const float* __restrict__ bq,
    const float* __restrict__ Wk, const float* __restrict__ bk,
    const float* __restrict__ Wv, const float* __restrict__ bv,
    ushort* __restrict__ qTp, ushort* __restrict__ kTp, ushort* __restrict__ vsw)
{
    __shared__ ushort vlds[32 * 68];   // [el][j], stride 68 halves (pad: no bank conflict)
    const int blk = blockIdx.x;
    const int tid = threadIdx.x;

    if (blk < 32) {   // ---------------- q/k path ----------------
        const int idx = blk * 512 + tid;
        const int b = idx >> 12, n = idx & (NN - 1);
        const float* xb = x + (size_t)b * CC * NN + n;
        float sq[8], sk[8];
#pragma unroll
        for (int d = 0; d < 8; ++d) { sq[d] = bq[d]; sk[d] = bk[d]; }
#pragma unroll
        for (int c = 0; c < CC; ++c) {
            const float xc = xb[c * NN];
#pragma unroll
            for (int d = 0; d < 8; ++d) {
                sq[d] += Wq[d * CC + c] * xc;
                sk[d] += Wk[d * CC + c] * xc;
            }
        }
        ushort hq[32], hk[32];
#pragma unroll
        for (int i = 0; i < 32; ++i) { hq[i] = 0; hk[i] = 0; }
#pragma unroll
        for (int d = 0; d < 8; ++d) { hq[d] = f2bf(sq[d]); hk[d] = f2bf(sk[d]); }
        hq[8]  = hq[0];                               // q0 hi
        hq[9]  = hq[1];                               // q1 hi
        hq[10] = f2bf(sq[0] - bf2f(hq[0]));           // q0 lo
        hq[11] = f2bf(sq[1] - bf2f(hq[1]));           // q1 lo
        const float col = (float)(n & 63), row = (float)(n >> 6);
        hk[8] = f2bf(col); hk[9] = f2bf(row); hk[10] = hk[8]; hk[11] = hk[9];

        uint4* dq = (uint4*)(qTp + (size_t)(b * NN + n) * 32);
        uint4* dk = (uint4*)(kTp + (size_t)(b * NN + n) * 32);
        const uint4* s4q = (const uint4*)hq;
        const uint4* s4k = (const uint4*)hk;
#pragma unroll
        for (int i = 0; i < 4; ++i) { dq[i] = s4q[i]; dk[i] = s4k[i]; }
        return;
    }

    // ---------------- v path: compute 32 ch x 64 px, LDS transpose, coalesced store ----------------
    const int w2 = blk - 32;
    const int bt = w2 >> 1, h = w2 & 1;               // h: channel half (0..1)
    const int b = bt >> 6, t = bt & 63;
    const int w = tid >> 6, j = tid & 63;             // wave -> 4 channels, lane -> pixel
    const int n = t * 64 + j;
    const int e0 = __builtin_amdgcn_readfirstlane(h * 32 + w * 4);   // eg base, wave-uniform

    const float* xb = x + (size_t)b * CC * NN + n;
    float a0 = bv[e0], a1 = bv[e0 + 1], a2 = bv[e0 + 2], a3 = bv[e0 + 3];
#pragma unroll
    for (int c = 0; c < CC; ++c) {
        const float xc = xb[c * NN];
        a0 += Wv[(e0 + 0) * CC + c] * xc;
        a1 += Wv[(e0 + 1) * CC + c] * xc;
        a2 += Wv[(e0 + 2) * CC + c] * xc;
        a3 += Wv[(e0 + 3) * CC + c] * xc;
    }
    const int el0 = w * 4;                            // local channel row in LDS
    vlds[(el0 + 0) * 68 + j] = f2bf(a0);
    vlds[(el0 + 1) * 68 + j] = f2bf(a1);
    vlds[(el0 + 2) * 68 + j] = f2bf(a2);
    vlds[(el0 + 3) * 68 + j] = f2bf(a3);
    __syncthreads();

    // store phase: tid -> (sb, hi, qd, el); one 8B coalesced store
    const int el = tid & 31;
    const int qd = (tid >> 5) & 3;
    const int sbh = tid >> 7;                         // 0..3
    const int sb = sbh >> 1, hi = sbh & 1;
    const int j0 = sb * 32 + hi * 16 + qd * 4;        // 4 contiguous pixels (r=0..3)
    const int eg = h * 32 + el;
    const uint2 val = *(const uint2*)(vlds + el * 68 + j0);
    const size_t tb = (size_t)(b * 64 + t) * 4096;
    *(uint2*)(vsw + tb + (size_t)(((sb * 4 + (eg >> 4)) * 64 + qd * 16 + (eg & 15)) * 8 + hi * 4)) = val;
}

// ---------------------------------------------------------------------------
// Kernel 2: MFMA attention — R15 VERBATIM + T5 setprio around the shared-PV
// MFMA cluster (scheduler hint; bit-identical output). 256 blocks x 512
// threads (8 waves), 64 queries/block (pair-loop), keys 8-way, inline loads,
// T13 defer (THR=25), exact flash combine, 4-stage epilogue.
// ---------------------------------------------------------------------------
__global__ __launch_bounds__(512) void attn_kernel(
    const ushort* __restrict__ qTp, const ushort* __restrict__ kTp,
    const ushort* __restrict__ vsw, float* __restrict__ out)
{
    const int blk = blockIdx.x;                  // 256 = B * N/64
    const int xcd = blk & 7, i8 = blk >> 3;      // i8: 0..31
    const int b  = xcd >> 1;                     // one b per XCD pair-slot
    const int nq = (((xcd & 1) << 5) | i8) << 6; // 64-query base (bijective)
    const int tid = threadIdx.x;
    const int wv = tid >> 6, lane = tid & 63;
    const int nn = lane & 15, quad = lane >> 4;

    __shared__ float Cb[8][1024];   // per-wave C-layout partials (one q-tile)
    __shared__ float Mx[8][64];
    __shared__ float Db[8][64];
    __shared__ float dn[64];

    // Q B-frags: lane holds q-channels quad*8..+8 of queries nq+qt*16+nn
    short8 qf[4];
#pragma unroll
    for (int qt = 0; qt < 4; ++qt)
        qf[qt] = *(const short8*)(qTp + ((size_t)(b * NN + nq + qt * 16 + nn) * 32 + quad * 8));
    const ushort* kb = kTp + (size_t)b * NN * 32;

    // ---------------- prepass: seed running max from this wave's first tile ----------------
    float m[4] = {-1e30f, -1e30f, -1e30f, -1e30f};
    {
        const int t = wv * 8;
#pragma unroll
        for (int p = 0; p < 2; ++p) {
            const int q0 = 2 * p, q1 = 2 * p + 1;
#pragma unroll
            for (int kg = 0; kg < 4; ++kg) {
                const short8 kf = *(const short8*)(kb + ((size_t)(t * 64 + kg * 16 + nn) * 32 + quad * 8));
                const f32x4 S0 = __builtin_amdgcn_mfma_f32_16x16x32_bf16(kf, qf[q0], (f32x4){0.f,0.f,0.f,0.f}, 0, 0, 0);
                const f32x4 S1 = __builtin_amdgcn_mfma_f32_16x16x32_bf16(kf, qf[q1], (f32x4){0.f,0.f,0.f,0.f}, 0, 0, 0);
                m[q0] = fmaxf(m[q0], fmaxf(fmaxf(S0[0], S0[1]), fmaxf(S0[2], S0[3])));
                m[q1] = fmaxf(m[q1], fmaxf(fmaxf(S1[0], S1[1]), fmaxf(S1[2], S1[3])));
            }
        }
#pragma unroll
        for (int qt = 0; qt < 4; ++qt) {
            m[qt] = fmaxf(m[qt], __shfl_xor(m[qt], 16, 64));
            m[qt] = fmaxf(m[qt], __shfl_xor(m[qt], 32, 64));
        }
    }
    f32x4 nM[4];
#pragma unroll
    for (int qt = 0; qt < 4; ++qt) nM[qt] = (f32x4){-m[qt], -m[qt], -m[qt], -m[qt]};

    // ---------------- single pass: S, deferred online max, exp, shared PV ----------------
    f32x4 acc[4][4];
#pragma unroll
    for (int qt = 0; qt < 4; ++qt)
#pragma unroll
        for (int g = 0; g < 4; ++g) acc[qt][g] = (f32x4){0.f,0.f,0.f,0.f};
    float dl[4] = {0.f, 0.f, 0.f, 0.f};

    for (int t8 = 0; t8 < 8; ++t8) {
        const int t = wv * 8 + t8;
        const ushort* vb = vsw + (size_t)(b * 64 + t) * 4096;
        unsigned pwA[4][8];                           // packed P for all 4 queries

#pragma unroll
        for (int p = 0; p < 2; ++p) {                 // softmax phase (R12 body per pair)
            const int q0 = 2 * p, q1 = 2 * p + 1;
            f32x4 s0[4], s1[4];
#pragma unroll
            for (int kg = 0; kg < 4; ++kg) {
                const short8 kf = *(const short8*)(kb + ((size_t)(t * 64 + kg * 16 + nn) * 32 + quad * 8));
                s0[kg] = __builtin_amdgcn_mfma_f32_16x16x32_bf16(kf, qf[q0], nM[q0], 0, 0, 0);   // s - m fused
                s1[kg] = __builtin_amdgcn_mfma_f32_16x16x32_bf16(kf, qf[q1], nM[q1], 0, 0, 0);
            }
            // per-query tile max (relative to running m)
            float r0 = fmaxf(fmaxf(s0[0][0], s0[0][1]), fmaxf(s0[0][2], s0[0][3]));
            float r1 = fmaxf(fmaxf(s1[0][0], s1[0][1]), fmaxf(s1[0][2], s1[0][3]));
#pragma unroll
            for (int kg = 1; kg < 4; ++kg) {
                r0 = fmaxf(r0, fmaxf(fmaxf(s0[kg][0], s0[kg][1]), fmaxf(s0[kg][2], s0[kg][3])));
                r1 = fmaxf(r1, fmaxf(fmaxf(s1[kg][0], s1[kg][1]), fmaxf(s1[kg][2], s1[kg][3])));
            }
            r0 = fmaxf(r0, __shfl_xor(r0, 16, 64));
            r0 = fmaxf(r0, __shfl_xor(r0, 32, 64));
            r1 = fmaxf(r1, __shfl_xor(r1, 16, 64));
            r1 = fmaxf(r1, __shfl_xor(r1, 32, 64));

            if (__any((r0 > 25.f) || (r1 > 25.f))) {  // T13: rare (growth > THR)
                const float d0 = fmaxf(r0, 0.f), d1 = fmaxf(r1, 0.f);
                const float e0 = __expf(-d0), e1 = __expf(-d1);
                m[q0] += d0; m[q1] += d1;
                nM[q0] = (f32x4){-m[q0], -m[q0], -m[q0], -m[q0]};
                nM[q1] = (f32x4){-m[q1], -m[q1], -m[q1], -m[q1]};
                dl[q0] *= e0; dl[q1] *= e1;           // per-query (nn) ✓
                f32x4 e0v, e1v;                       // per-query (quad*4+rr) for acc
#pragma unroll
                for (int rr = 0; rr < 4; ++rr) {
                    e0v[rr] = __shfl(e0, quad * 4 + rr, 64);
                    e1v[rr] = __shfl(e1, quad * 4 + rr, 64);
                }
#pragma unroll
                for (int g = 0; g < 4; ++g) { acc[q0][g] *= e0v; acc[q1][g] *= e1v; }
                const f32x4 dv0 = {d0, d0, d0, d0}, dv1 = {d1, d1, d1, d1};
#pragma unroll
                for (int kg = 0; kg < 4; ++kg) { s0[kg] -= dv0; s1[kg] -= dv1; }
            }

#pragma unroll
            for (int kg = 0; kg < 4; ++kg) {
                const float w00 = __expf(s0[kg][0]), w01 = __expf(s0[kg][1]);
                const float w02 = __expf(s0[kg][2]), w03 = __expf(s0[kg][3]);
                const float w10 = __expf(s1[kg][0]), w11 = __expf(s1[kg][1]);
                const float w12 = __expf(s1[kg][2]), w13 = __expf(s1[kg][3]);
                dl[q0] += (w00 + w01) + (w02 + w03);
                dl[q1] += (w10 + w11) + (w12 + w13);
                pwA[q0][2 * kg]     = cvt_pk_bf16(w00, w01);
                pwA[q0][2 * kg + 1] = cvt_pk_bf16(w02, w03);
                pwA[q1][2 * kg]     = cvt_pk_bf16(w10, w11);
                pwA[q1][2 * kg + 1] = cvt_pk_bf16(w12, w13);
            }
        }

        // ---- shared PV: each vf loaded ONCE (inline), feeds all 4 queries ----
        __builtin_amdgcn_s_setprio(1);                // T5: favor MFMA-entering wave
#pragma unroll
        for (int sb = 0; sb < 2; ++sb) {
            short8 af[4];
#pragma unroll
            for (int qt = 0; qt < 4; ++qt) {
                const uint4v u = {pwA[qt][4 * sb], pwA[qt][4 * sb + 1],
                                  pwA[qt][4 * sb + 2], pwA[qt][4 * sb + 3]};
                af[qt] = __builtin_bit_cast(short8, u);
            }
#pragma unroll
            for (int g = 0; g < 4; ++g) {
                const short8 vf = *(const short8*)(vb + sb * 2048 + g * 512 + lane * 8);
                acc[0][g] = __builtin_amdgcn_mfma_f32_16x16x32_bf16(af[0], vf, acc[0][g], 0, 0, 0);
                acc[1][g] = __builtin_amdgcn_mfma_f32_16x16x32_bf16(af[1], vf, acc[1][g], 0, 0, 0);
                acc[2][g] = __builtin_amdgcn_mfma_f32_16x16x32_bf16(af[2], vf, acc[2][g], 0, 0, 0);
                acc[3][g] = __builtin_amdgcn_mfma_f32_16x16x32_bf16(af[3], vf, acc[3][g], 0, 0, 0);
            }
        }
        __builtin_amdgcn_s_setprio(0);
    }

    // ---------------- exact cross-wave flash combine ----------------
    if (quad == 0) {
#pragma unroll
        for (int qt = 0; qt < 4; ++qt) Mx[wv][qt * 16 + nn] = m[qt];
    }
    __syncthreads();
#pragma unroll
    for (int qt = 0; qt < 4; ++qt) {
        float M = Mx[0][qt * 16 + nn];
#pragma unroll
        for (int w = 1; w < 8; ++w) M = fmaxf(M, Mx[w][qt * 16 + nn]);
        const float gq = __expf(m[qt] - M);           // <= 1
        dl[qt] *= gq;
        f32x4 gv;
#pragma unroll
        for (int rr = 0; rr < 4; ++rr) gv[rr] = __shfl(gq, quad * 4 + rr, 64);
#pragma unroll
        for (int g = 0; g < 4; ++g) acc[qt][g] *= gv;
        dl[qt] += __shfl_xor(dl[qt], 16, 64);
        dl[qt] += __shfl_xor(dl[qt], 32, 64);
    }
    if (quad == 0) {
#pragma unroll
        for (int qt = 0; qt < 4; ++qt) Db[wv][qt * 16 + nn] = dl[qt];
    }

#pragma unroll
    for (int qt = 0; qt < 4; ++qt) {
#pragma unroll
        for (int g = 0; g < 4; ++g)
#pragma unroll
            for (int r = 0; r < 4; ++r)
                Cb[wv][(g * 4 + r) * 64 + lane] = acc[qt][g][r];
        __syncthreads();
        if (qt == 0) {
            if (tid < 64) {
                float s = Db[0][tid];
#pragma unroll
                for (int w = 1; w < 8; ++w) s += Db[w][tid];
                dn[tid] = s;
            }
            __syncthreads();
        }
#pragma unroll
        for (int it = 0; it < 2; ++it) {
            const int e = tid + it * 512;
            const int q = e & 15, c = e >> 4;
            const int src = ((c >> 4) * 4 + (q & 3)) * 64 + (q >> 2) * 16 + (c & 15);
            float v = Cb[0][src];
#pragma unroll
            for (int w = 1; w < 8; ++w) v += Cb[w][src];
            out[(size_t)(b * CC + c) * NN + nq + qt * 16 + q] = v / dn[qt * 16 + q];
        }
        __syncthreads();
    }
}

extern "C" void kernel_launch(void* const* d_in, const int* in_sizes, int n_in,
                              void* d_out, int out_size, void* d_ws, size_t ws_size,
                              hipStream_t stream) {
    const float* x  = (const float*)d_in[0];
    const float* Wq = (const float*)d_in[1];
    const float* bq = (const float*)d_in[2];
    const float* Wk = (const float*)d_in[3];
    const float* bk = (const float*)d_in[4];
    const float* Wv = (const float*)d_in[5];
    const float* bv = (const float*)d_in[6];
    float* out = (float*)d_out;

    ushort* ws  = (ushort*)d_ws;
    ushort* qTp = ws;                                  // B*N*32 halves (1 MB)
    ushort* kTp = ws + (size_t)BB * NN * 32;           // B*N*32 halves (1 MB)
    ushort* vsw = ws + (size_t)2 * BB * NN * 32;       // B*64*4096 halves (2 MB)

    qkv_kernel<<<544, 512, 0, stream>>>(x, Wq, bq, Wk, bk, Wv, bv, qTp, kTp, vsw);
    attn_kernel<<<256, 512, 0, stream>>>(qTp, kTp, vsw, out);
}

// Round 21
// 108.889 us; speedup vs baseline: 1.0469x; 1.0469x over previous
//
#include <hip/hip_runtime.h>

// B,C,H,W = 4,64,64,64 ; N = 4096 ; d = 8
#define BB 4
#define CC 64
#define NN 4096

typedef __attribute__((ext_vector_type(8))) short short8;
typedef __attribute__((ext_vector_type(4))) float f32x4;
typedef __attribute__((ext_vector_type(4))) unsigned uint4v;

__device__ inline ushort f2bf(float x) {                 // RNE float->bf16
    unsigned u = __float_as_uint(x);
    return (ushort)((u + 0x7fff + ((u >> 16) & 1)) >> 16);
}
__device__ inline float bf2f(ushort h) { return __uint_as_float(((unsigned)h) << 16); }

__device__ inline unsigned cvt_pk_bf16(float a, float b) {   // lo=bf16(a), hi=bf16(b)
    unsigned r;
    asm("v_cvt_pk_bf16_f32 %0, %1, %2" : "=v"(r) : "v"(a), "v"(b));
    return r;
}

// ws layout (ushort):
//   qTp [B][N][32] : q0..q7, q0h,q1h,q0l,q1l, 0*20                     (1 MB)
//   kTp [B][N][32] : k0..k7, col,row,col,row, 0*20                     (1 MB)
//   vsw [B][64 tiles][2 sb][4 g][64 lanes][8 jj]                       (2 MB)
//     KEY-PERMUTED B-frag: physical key j (kg=j>>4, qd=(j>>2)&3, r=j&3) is
//     stored at (sb=kg>>1, lane=qd*16+(e&15), jj=((kg&1)<<2)|r) so the PV
//     A-operand is exactly the lane-local cvt_pk output of the S-MFMA.
//
// SESSION FINAL STATE: R19/R15 verified best (109.5us, absmax 0.046875).
// R20's two micro-levers (qkv full unroll, attn setprio) regressed -4.5us
// -> both reverted. Lever matrix complete:
//   attn: work removal flat, traffic halving flat, shared-PV -1.8us (kept),
//         TLP blocked by compiler (64-VGPR pin, 3 directives tried),
//         setprio regression.
//   qkv:  store coalescing flat, 4ch/thread flat, full unroll regression.
// Budget: fill 41us (82% HBM, its own roofline) + harness overhead ~32us +
// qkv 11.8us + attn 24.1us (both latency-bound, levers exhausted).
//
// EMPIRICAL RULE (R2/R3/R4/R7 vs R1/R8-R20): never stage K/V tiles into
// short8 REGISTER ARRAYS in attn; all kf/vf loads inline single-vars.

// ---------------------------------------------------------------------------
// Kernel 1: QKV projection — R11 VERBATIM (harness-verified, absmax 0.047).
// ---------------------------------------------------------------------------
__global__ __launch_bounds__(512) void qkv_kernel(
    const float* __restrict__ x,
    const float* __restrict__ Wq, const float* __restrict__ bq,
    const float* __restrict__ Wk, const float* __restrict__ bk,
    const float* __restrict__ Wv, const float* __restrict__ bv,
    ushort* __restrict__ qTp, ushort* __restrict__ kTp, ushort* __restrict__ vsw)
{
    __shared__ ushort vlds[32 * 68];   // [el][j], stride 68 halves (pad: no bank conflict)
    const int blk = blockIdx.x;
    const int tid = threadIdx.x;

    if (blk < 32) {   // ---------------- q/k path (round-1 body, 512-thr grid) ----------------
        const int idx = blk * 512 + tid;
        const int b = idx >> 12, n = idx & (NN - 1);
        const float* xb = x + (size_t)b * CC * NN + n;
        float sq[8], sk[8];
#pragma unroll
        for (int d = 0; d < 8; ++d) { sq[d] = bq[d]; sk[d] = bk[d]; }
#pragma unroll 8
        for (int c = 0; c < CC; ++c) {
            const float xc = xb[c * NN];
#pragma unroll
            for (int d = 0; d < 8; ++d) {
                sq[d] += Wq[d * CC + c] * xc;
                sk[d] += Wk[d * CC + c] * xc;
            }
        }
        ushort hq[32], hk[32];
#pragma unroll
        for (int i = 0; i < 32; ++i) { hq[i] = 0; hk[i] = 0; }
#pragma unroll
        for (int d = 0; d < 8; ++d) { hq[d] = f2bf(sq[d]); hk[d] = f2bf(sk[d]); }
        hq[8]  = hq[0];                               // q0 hi
        hq[9]  = hq[1];                               // q1 hi
        hq[10] = f2bf(sq[0] - bf2f(hq[0]));           // q0 lo
        hq[11] = f2bf(sq[1] - bf2f(hq[1]));           // q1 lo
        const float col = (float)(n & 63), row = (float)(n >> 6);
        hk[8] = f2bf(col); hk[9] = f2bf(row); hk[10] = hk[8]; hk[11] = hk[9];

        uint4* dq = (uint4*)(qTp + (size_t)(b * NN + n) * 32);
        uint4* dk = (uint4*)(kTp + (size_t)(b * NN + n) * 32);
        const uint4* s4q = (const uint4*)hq;
        const uint4* s4k = (const uint4*)hk;
#pragma unroll
        for (int i = 0; i < 4; ++i) { dq[i] = s4q[i]; dk[i] = s4k[i]; }
        return;
    }

    // ---------------- v path: compute 32 ch x 64 px, LDS transpose, coalesced store ----------------
    const int w2 = blk - 32;
    const int bt = w2 >> 1, h = w2 & 1;               // h: channel half (0..1)
    const int b = bt >> 6, t = bt & 63;
    const int w = tid >> 6, j = tid & 63;             // wave -> 4 channels, lane -> pixel
    const int n = t * 64 + j;
    const int e0 = __builtin_amdgcn_readfirstlane(h * 32 + w * 4);   // eg base, wave-uniform

    const float* xb = x + (size_t)b * CC * NN + n;
    float a0 = bv[e0], a1 = bv[e0 + 1], a2 = bv[e0 + 2], a3 = bv[e0 + 3];
#pragma unroll 8
    for (int c = 0; c < CC; ++c) {
        const float xc = xb[c * NN];
        a0 += Wv[(e0 + 0) * CC + c] * xc;
        a1 += Wv[(e0 + 1) * CC + c] * xc;
        a2 += Wv[(e0 + 2) * CC + c] * xc;
        a3 += Wv[(e0 + 3) * CC + c] * xc;
    }
    const int el0 = w * 4;                            // local channel row in LDS
    vlds[(el0 + 0) * 68 + j] = f2bf(a0);
    vlds[(el0 + 1) * 68 + j] = f2bf(a1);
    vlds[(el0 + 2) * 68 + j] = f2bf(a2);
    vlds[(el0 + 3) * 68 + j] = f2bf(a3);
    __syncthreads();

    // store phase: tid -> (sb, hi, qd, el); one 8B coalesced store
    const int el = tid & 31;
    const int qd = (tid >> 5) & 3;
    const int sbh = tid >> 7;                         // 0..3
    const int sb = sbh >> 1, hi = sbh & 1;
    const int j0 = sb * 32 + hi * 16 + qd * 4;        // 4 contiguous pixels (r=0..3)
    const int eg = h * 32 + el;
    const uint2 val = *(const uint2*)(vlds + el * 68 + j0);
    const size_t tb = (size_t)(b * 64 + t) * 4096;
    *(uint2*)(vsw + tb + (size_t)(((sb * 4 + (eg >> 4)) * 64 + qd * 16 + (eg & 15)) * 8 + hi * 4)) = val;
}

// ---------------------------------------------------------------------------
// Kernel 2: MFMA attention — R15 VERBATIM (harness-verified best: total
// 109.5us, absmax 0.046875). 256 blocks x 512 threads (8 waves), 64
// queries/block (pair-loop), keys 8-way. Per t8: both pairs' softmax/pack
// first (pwA[4][8]), then ONE shared PV section (each vf loaded once,
// inline, feeds all 4 queries). Online softmax w/ T13 defer (THR=25),
// exact flash combine, 4-stage epilogue.
// ---------------------------------------------------------------------------
__global__ __launch_bounds__(512) void attn_kernel(
    const ushort* __restrict__ qTp, const ushort* __restrict__ kTp,
    const ushort* __restrict__ vsw, float* __restrict__ out)
{
    const int blk = blockIdx.x;                  // 256 = B * N/64
    const int xcd = blk & 7, i8 = blk >> 3;      // i8: 0..31
    const int b  = xcd >> 1;                     // one b per XCD pair-slot
    const int nq = (((xcd & 1) << 5) | i8) << 6; // 64-query base (bijective)
    const int tid = threadIdx.x;
    const int wv = tid >> 6, lane = tid & 63;
    const int nn = lane & 15, quad = lane >> 4;

    __shared__ float Cb[8][1024];   // per-wave C-layout partials (one q-tile)
    __shared__ float Mx[8][64];
    __shared__ float Db[8][64];
    __shared__ float dn[64];

    // Q B-frags: lane holds q-channels quad*8..+8 of queries nq+qt*16+nn
    short8 qf[4];
#pragma unroll
    for (int qt = 0; qt < 4; ++qt)
        qf[qt] = *(const short8*)(qTp + ((size_t)(b * NN + nq + qt * 16 + nn) * 32 + quad * 8));
    const ushort* kb = kTp + (size_t)b * NN * 32;

    // ---------------- prepass: seed running max from this wave's first tile ----------------
    float m[4] = {-1e30f, -1e30f, -1e30f, -1e30f};
    {
        const int t = wv * 8;
#pragma unroll
        for (int p = 0; p < 2; ++p) {
            const int q0 = 2 * p, q1 = 2 * p + 1;
#pragma unroll
            for (int kg = 0; kg < 4; ++kg) {
                const short8 kf = *(const short8*)(kb + ((size_t)(t * 64 + kg * 16 + nn) * 32 + quad * 8));
                const f32x4 S0 = __builtin_amdgcn_mfma_f32_16x16x32_bf16(kf, qf[q0], (f32x4){0.f,0.f,0.f,0.f}, 0, 0, 0);
                const f32x4 S1 = __builtin_amdgcn_mfma_f32_16x16x32_bf16(kf, qf[q1], (f32x4){0.f,0.f,0.f,0.f}, 0, 0, 0);
                m[q0] = fmaxf(m[q0], fmaxf(fmaxf(S0[0], S0[1]), fmaxf(S0[2], S0[3])));
                m[q1] = fmaxf(m[q1], fmaxf(fmaxf(S1[0], S1[1]), fmaxf(S1[2], S1[3])));
            }
        }
#pragma unroll
        for (int qt = 0; qt < 4; ++qt) {
            m[qt] = fmaxf(m[qt], __shfl_xor(m[qt], 16, 64));
            m[qt] = fmaxf(m[qt], __shfl_xor(m[qt], 32, 64));
        }
    }
    f32x4 nM[4];
#pragma unroll
    for (int qt = 0; qt < 4; ++qt) nM[qt] = (f32x4){-m[qt], -m[qt], -m[qt], -m[qt]};

    // ---------------- single pass: S, deferred online max, exp, shared PV ----------------
    f32x4 acc[4][4];
#pragma unroll
    for (int qt = 0; qt < 4; ++qt)
#pragma unroll
        for (int g = 0; g < 4; ++g) acc[qt][g] = (f32x4){0.f,0.f,0.f,0.f};
    float dl[4] = {0.f, 0.f, 0.f, 0.f};

    for (int t8 = 0; t8 < 8; ++t8) {
        const int t = wv * 8 + t8;
        const ushort* vb = vsw + (size_t)(b * 64 + t) * 4096;
        unsigned pwA[4][8];                           // packed P for all 4 queries

#pragma unroll
        for (int p = 0; p < 2; ++p) {                 // softmax phase (R12 body per pair)
            const int q0 = 2 * p, q1 = 2 * p + 1;
            f32x4 s0[4], s1[4];
#pragma unroll
            for (int kg = 0; kg < 4; ++kg) {
                const short8 kf = *(const short8*)(kb + ((size_t)(t * 64 + kg * 16 + nn) * 32 + quad * 8));
                s0[kg] = __builtin_amdgcn_mfma_f32_16x16x32_bf16(kf, qf[q0], nM[q0], 0, 0, 0);   // s - m fused
                s1[kg] = __builtin_amdgcn_mfma_f32_16x16x32_bf16(kf, qf[q1], nM[q1], 0, 0, 0);
            }
            // per-query tile max (relative to running m)
            float r0 = fmaxf(fmaxf(s0[0][0], s0[0][1]), fmaxf(s0[0][2], s0[0][3]));
            float r1 = fmaxf(fmaxf(s1[0][0], s1[0][1]), fmaxf(s1[0][2], s1[0][3]));
#pragma unroll
            for (int kg = 1; kg < 4; ++kg) {
                r0 = fmaxf(r0, fmaxf(fmaxf(s0[kg][0], s0[kg][1]), fmaxf(s0[kg][2], s0[kg][3])));
                r1 = fmaxf(r1, fmaxf(fmaxf(s1[kg][0], s1[kg][1]), fmaxf(s1[kg][2], s1[kg][3])));
            }
            r0 = fmaxf(r0, __shfl_xor(r0, 16, 64));
            r0 = fmaxf(r0, __shfl_xor(r0, 32, 64));
            r1 = fmaxf(r1, __shfl_xor(r1, 16, 64));
            r1 = fmaxf(r1, __shfl_xor(r1, 32, 64));

            if (__any((r0 > 25.f) || (r1 > 25.f))) {  // T13: rare (growth > THR)
                const float d0 = fmaxf(r0, 0.f), d1 = fmaxf(r1, 0.f);
                const float e0 = __expf(-d0), e1 = __expf(-d1);
                m[q0] += d0; m[q1] += d1;
                nM[q0] = (f32x4){-m[q0], -m[q0], -m[q0], -m[q0]};
                nM[q1] = (f32x4){-m[q1], -m[q1], -m[q1], -m[q1]};
                dl[q0] *= e0; dl[q1] *= e1;           // per-query (nn) ✓
                f32x4 e0v, e1v;                       // per-query (quad*4+rr) for acc
#pragma unroll
                for (int rr = 0; rr < 4; ++rr) {
                    e0v[rr] = __shfl(e0, quad * 4 + rr, 64);
                    e1v[rr] = __shfl(e1, quad * 4 + rr, 64);
                }
#pragma unroll
                for (int g = 0; g < 4; ++g) { acc[q0][g] *= e0v; acc[q1][g] *= e1v; }
                const f32x4 dv0 = {d0, d0, d0, d0}, dv1 = {d1, d1, d1, d1};
#pragma unroll
                for (int kg = 0; kg < 4; ++kg) { s0[kg] -= dv0; s1[kg] -= dv1; }
            }

#pragma unroll
            for (int kg = 0; kg < 4; ++kg) {
                const float w00 = __expf(s0[kg][0]), w01 = __expf(s0[kg][1]);
                const float w02 = __expf(s0[kg][2]), w03 = __expf(s0[kg][3]);
                const float w10 = __expf(s1[kg][0]), w11 = __expf(s1[kg][1]);
                const float w12 = __expf(s1[kg][2]), w13 = __expf(s1[kg][3]);
                dl[q0] += (w00 + w01) + (w02 + w03);
                dl[q1] += (w10 + w11) + (w12 + w13);
                pwA[q0][2 * kg]     = cvt_pk_bf16(w00, w01);
                pwA[q0][2 * kg + 1] = cvt_pk_bf16(w02, w03);
                pwA[q1][2 * kg]     = cvt_pk_bf16(w10, w11);
                pwA[q1][2 * kg + 1] = cvt_pk_bf16(w12, w13);
            }
        }

        // ---- shared PV: each vf loaded ONCE (inline), feeds all 4 queries ----
#pragma unroll
        for (int sb = 0; sb < 2; ++sb) {
            short8 af[4];
#pragma unroll
            for (int qt = 0; qt < 4; ++qt) {
                const uint4v u = {pwA[qt][4 * sb], pwA[qt][4 * sb + 1],
                                  pwA[qt][4 * sb + 2], pwA[qt][4 * sb + 3]};
                af[qt] = __builtin_bit_cast(short8, u);
            }
#pragma unroll
            for (int g = 0; g < 4; ++g) {
                const short8 vf = *(const short8*)(vb + sb * 2048 + g * 512 + lane * 8);
                acc[0][g] = __builtin_amdgcn_mfma_f32_16x16x32_bf16(af[0], vf, acc[0][g], 0, 0, 0);
                acc[1][g] = __builtin_amdgcn_mfma_f32_16x16x32_bf16(af[1], vf, acc[1][g], 0, 0, 0);
                acc[2][g] = __builtin_amdgcn_mfma_f32_16x16x32_bf16(af[2], vf, acc[2][g], 0, 0, 0);
                acc[3][g] = __builtin_amdgcn_mfma_f32_16x16x32_bf16(af[3], vf, acc[3][g], 0, 0, 0);
            }
        }
    }

    // ---------------- exact cross-wave flash combine ----------------
    if (quad == 0) {
#pragma unroll
        for (int qt = 0; qt < 4; ++qt) Mx[wv][qt * 16 + nn] = m[qt];
    }
    __syncthreads();
#pragma unroll
    for (int qt = 0; qt < 4; ++qt) {
        float M = Mx[0][qt * 16 + nn];
#pragma unroll
        for (int w = 1; w < 8; ++w) M = fmaxf(M, Mx[w][qt * 16 + nn]);
        const float gq = __expf(m[qt] - M);           // <= 1
        dl[qt] *= gq;
        f32x4 gv;
#pragma unroll
        for (int rr = 0; rr < 4; ++rr) gv[rr] = __shfl(gq, quad * 4 + rr, 64);
#pragma unroll
        for (int g = 0; g < 4; ++g) acc[qt][g] *= gv;
        dl[qt] += __shfl_xor(dl[qt], 16, 64);
        dl[qt] += __shfl_xor(dl[qt], 32, 64);
    }
    if (quad == 0) {
#pragma unroll
        for (int qt = 0; qt < 4; ++qt) Db[wv][qt * 16 + nn] = dl[qt];
    }

#pragma unroll
    for (int qt = 0; qt < 4; ++qt) {
#pragma unroll
        for (int g = 0; g < 4; ++g)
#pragma unroll
            for (int r = 0; r < 4; ++r)
                Cb[wv][(g * 4 + r) * 64 + lane] = acc[qt][g][r];
        __syncthreads();
        if (qt == 0) {
            if (tid < 64) {
                float s = Db[0][tid];
#pragma unroll
                for (int w = 1; w < 8; ++w) s += Db[w][tid];
                dn[tid] = s;
            }
            __syncthreads();
        }
#pragma unroll
        for (int it = 0; it < 2; ++it) {
            const int e = tid + it * 512;
            const int q = e & 15, c = e >> 4;
            const int src = ((c >> 4) * 4 + (q & 3)) * 64 + (q >> 2) * 16 + (c & 15);
            float v = Cb[0][src];
#pragma unroll
            for (int w = 1; w < 8; ++w) v += Cb[w][src];
            out[(size_t)(b * CC + c) * NN + nq + qt * 16 + q] = v / dn[qt * 16 + q];
        }
        __syncthreads();
    }
}

extern "C" void kernel_launch(void* const* d_in, const int* in_sizes, int n_in,
                              void* d_out, int out_size, void* d_ws, size_t ws_size,
                              hipStream_t stream) {
    const float* x  = (const float*)d_in[0];
    const float* Wq = (const float*)d_in[1];
    const float* bq = (const float*)d_in[2];
    const float* Wk = (const float*)d_in[3];
    const float* bk = (const float*)d_in[4];
    const float* Wv = (const float*)d_in[5];
    const float* bv = (const float*)d_in[6];
    float* out = (float*)d_out;

    ushort* ws  = (ushort*)d_ws;
    ushort* qTp = ws;                                  // B*N*32 halves (1 MB)
    ushort* kTp = ws + (size_t)BB * NN * 32;           // B*N*32 halves (1 MB)
    ushort* vsw = ws + (size_t)2 * BB * NN * 32;       // B*64*4096 halves (2 MB)

    qkv_kernel<<<544, 512, 0, stream>>>(x, Wq, bq, Wk, bk, Wv, bv, qTp, kTp, vsw);
    attn_kernel<<<256, 512, 0, stream>>>(qTp, kTp, vsw, out);
}